// Round 4
// baseline (230.996 us; speedup 1.0000x reference)
//
#include <hip/hip_runtime.h>

typedef __attribute__((ext_vector_type(8))) short short8;     // 8 bf16 MFMA operand
typedef __attribute__((ext_vector_type(4))) float f32x4;
typedef __attribute__((ext_vector_type(8))) unsigned short ushort8v;

// B=2, T=2048, D_IN=1024, H=16, D_HEAD=64, D_INNER=1024, M=B*T=4096

__device__ __forceinline__ unsigned short f2bf(float f) {
  union { float f; unsigned int u; } x; x.f = f;
  unsigned int r = x.u + 0x7FFFu + ((x.u >> 16) & 1u);   // RNE
  return (unsigned short)(r >> 16);
}

__device__ __forceinline__ void gload_lds16(const void* g, void* l) {
  __builtin_amdgcn_global_load_lds(
      (const __attribute__((address_space(1))) void*)g,
      (__attribute__((address_space(3))) void*)l, 16, 0, 0);
}

// ---------------- prep kernels ----------------

__global__ void cvt_bf16(const float* __restrict__ src, unsigned short* __restrict__ dst, int n) {
  int i = (blockIdx.x * blockDim.x + threadIdx.x) * 4;
  if (i < n) {
    float4 f = *(const float4*)(src + i);
    ushort4 o;
    o.x = f2bf(f.x); o.y = f2bf(f.y); o.z = f2bf(f.z); o.w = f2bf(f.w);
    *(ushort4*)(dst + i) = o;
  }
}

// dst[n][k] = (bf16) src[k][n]; z selects among 3 weight matrices (1024x1024)
__global__ void transpose_cvt3(const float* __restrict__ s0, const float* __restrict__ s1,
                               const float* __restrict__ s2,
                               unsigned short* __restrict__ d0, unsigned short* __restrict__ d1,
                               unsigned short* __restrict__ d2) {
  const float* src = (blockIdx.z == 0) ? s0 : (blockIdx.z == 1) ? s1 : s2;
  unsigned short* dst = (blockIdx.z == 0) ? d0 : (blockIdx.z == 1) ? d1 : d2;
  __shared__ float tile[32][33];
  int kx = blockIdx.x * 32, ny = blockIdx.y * 32;
  int tx = threadIdx.x & 31, ty = threadIdx.x >> 5;  // 32x8
  #pragma unroll
  for (int r = 0; r < 32; r += 8)
    tile[ty + r][tx] = src[(size_t)(kx + ty + r) * 1024 + ny + tx];
  __syncthreads();
  #pragma unroll
  for (int r = 0; r < 32; r += 8)
    dst[(size_t)(ny + ty + r) * 1024 + kx + tx] = f2bf(tile[tx][ty + r]);
}

__global__ void transpose_cvt(const float* __restrict__ src, unsigned short* __restrict__ dst,
                              int K, int N) {
  __shared__ float tile[32][33];
  int kx = blockIdx.x * 32, ny = blockIdx.y * 32;
  int tx = threadIdx.x & 31, ty = threadIdx.x >> 5;
  #pragma unroll
  for (int r = 0; r < 32; r += 8)
    tile[ty + r][tx] = src[(size_t)(kx + ty + r) * N + ny + tx];
  __syncthreads();
  #pragma unroll
  for (int r = 0; r < 32; r += 8)
    dst[(size_t)(ny + ty + r) * K + kx + tx] = f2bf(tile[tx][ty + r]);
}

// ---------------- QKV projection GEMM, BK=64 with XOR-swizzled staging ----------------
// LDS layout: As[row][cb'*8+j] holds logical col-block cb = cb' ^ (row&7).
// Staging swizzles the GLOBAL source per lane (gc8 = c8 ^ (row&7)) since
// global_load_lds LDS dst is wave-uniform-base + lane*16 (no padding allowed).
// Frag read at cb' = (s*4+quad) ^ (l15&7) -> logical k = s*32+quad*8, bank-balanced.

__global__ __launch_bounds__(256) void qkv_gemm(
    const unsigned short* __restrict__ Xb,
    const unsigned short* __restrict__ Wqt, const unsigned short* __restrict__ Wkt,
    const unsigned short* __restrict__ Wvt,
    unsigned short* __restrict__ Oq, unsigned short* __restrict__ Ok,
    unsigned short* __restrict__ Ovt) {
  constexpr int Kd = 1024;
  __shared__ __align__(16) unsigned short As[128 * 64];
  __shared__ __align__(16) unsigned short Bs[128 * 64];
  int z = blockIdx.z;
  int m0, n0;
  const unsigned short *Arow, *Brow;
  if (z == 2) {  // V^T: m over d_inner, n over tokens
    m0 = blockIdx.y * 128; n0 = blockIdx.x * 128;
    Arow = Wvt; Brow = Xb;
  } else {
    m0 = blockIdx.x * 128; n0 = blockIdx.y * 128;
    Arow = Xb; Brow = (z == 0) ? Wqt : Wkt;
  }
  int tid = threadIdx.x, lane = tid & 63, wave = tid >> 6;
  int wm = wave >> 1, wn = wave & 1;
  int l15 = lane & 15, quad = lane >> 4;
  int swz = l15 & 7;

  f32x4 acc[4][4] = {};

  for (int k0 = 0; k0 < Kd; k0 += 64) {
    __syncthreads();
    #pragma unroll
    for (int r = 0; r < 4; ++r) {
      int i = tid + 256 * r;
      int row = i >> 3, c8 = i & 7;
      int gc8 = c8 ^ (row & 7);
      gload_lds16(Arow + (size_t)(m0 + row) * Kd + k0 + gc8 * 8, &As[i * 8]);
    }
    #pragma unroll
    for (int r = 0; r < 4; ++r) {
      int i = tid + 256 * r;
      int row = i >> 3, c8 = i & 7;
      int gc8 = c8 ^ (row & 7);
      gload_lds16(Brow + (size_t)(n0 + row) * Kd + k0 + gc8 * 8, &Bs[i * 8]);
    }
    __syncthreads();
    short8 af[4][2], bf[4][2];
    #pragma unroll
    for (int s = 0; s < 2; ++s) {
      #pragma unroll
      for (int i = 0; i < 4; ++i)
        af[i][s] = *(const short8*)&As[(wm * 64 + i * 16 + l15) * 64 + (((s << 2) + quad) ^ swz) * 8];
      #pragma unroll
      for (int j = 0; j < 4; ++j)
        bf[j][s] = *(const short8*)&Bs[(wn * 64 + j * 16 + l15) * 64 + (((s << 2) + quad) ^ swz) * 8];
    }
    #pragma unroll
    for (int s = 0; s < 2; ++s)
      #pragma unroll
      for (int i = 0; i < 4; ++i)
        #pragma unroll
        for (int j = 0; j < 4; ++j)
          acc[i][j] = __builtin_amdgcn_mfma_f32_16x16x32_bf16(af[i][s], bf[j][s], acc[i][j], 0, 0, 0);
  }

  if (z == 2) {
    #pragma unroll
    for (int i = 0; i < 4; ++i) {
      int dmbase = m0 + wm * 64 + i * 16 + quad * 4;
      #pragma unroll
      for (int j = 0; j < 4; ++j) {
        int tn = n0 + wn * 64 + j * 16 + l15;
        int b = tn >> 11, t = tn & 2047;
        #pragma unroll
        for (int r = 0; r < 4; ++r) {
          int dm = dmbase + r;
          int h = dm >> 6, d = dm & 63;
          Ovt[(((size_t)(b * 16 + h) * 64 + d) << 11) + t] = f2bf(acc[i][j][r]);
        }
      }
    }
  } else {
    unsigned short* O = (z == 0) ? Oq : Ok;
    float scale = (z == 0) ? 0.03125f : 1.0f;  // 1/sqrt(1024) folded into Q
    #pragma unroll
    for (int i = 0; i < 4; ++i) {
      int mbase = m0 + wm * 64 + i * 16 + quad * 4;
      #pragma unroll
      for (int j = 0; j < 4; ++j) {
        int n = n0 + wn * 64 + j * 16 + l15;
        int h = n >> 6, d = n & 63;
        #pragma unroll
        for (int r = 0; r < 4; ++r) {
          int mm = mbase + r;
          int b = mm >> 11, t = mm & 2047;
          size_t off = (((size_t)(b * 16 + h) * 2048 + t) << 6) + d;
          O[off] = f2bf(acc[i][j][r] * scale);
        }
      }
    }
  }
}

// ---------------- fused causal flash attention v3 ----------------
// No K/V LDS, no barriers: K loaded straight from global in A-frag layout,
// V^T straight from global in B-frag layout (both 16B/lane). 2-wave blocks,
// 32 q/wave (64-row q-tile). LDS only for the wave-private P C->A round trip.

__global__ __launch_bounds__(128, 2) void attn3(
    const unsigned short* __restrict__ Qg, const unsigned short* __restrict__ Kg,
    const unsigned short* __restrict__ Vtg, unsigned short* __restrict__ Yg) {
  constexpr int T = 2048;
  __shared__ __align__(16) unsigned short Ps[2][32 * 72];
  int bh = blockIdx.y;
  int qt = (blockIdx.x + blockIdx.y) & 31;
  int tid = threadIdx.x, lane = tid & 63, wave = tid >> 6;
  int l15 = lane & 15, quad = lane >> 4;
  const unsigned short* Qb = Qg + (size_t)bh * T * 64;
  const unsigned short* Kb = Kg + (size_t)bh * T * 64;
  const unsigned short* Vb = Vtg + (size_t)bh * 64 * T;
  int qw = qt * 64 + wave * 32;

  // Q as B-operand frags, held in regs: lane n=q(l15), k=d(quad*8+32s)
  short8 qf[2][2];
  #pragma unroll
  for (int jq = 0; jq < 2; ++jq)
    #pragma unroll
    for (int s = 0; s < 2; ++s)
      qf[jq][s] = *(const short8*)(Qb + (size_t)(qw + jq * 16 + l15) * 64 + quad * 8 + 32 * s);

  f32x4 Oacc[2][4] = {};
  float m_run[2] = {-__builtin_inff(), -__builtin_inff()};
  float l_run[2] = {0.f, 0.f};

  for (int kt = 0; kt <= qt; ++kt) {
    // K as A-operand frags direct from global: lane m=tok(mi*16+l15), k=d
    short8 kf[4][2];
    #pragma unroll
    for (int mi = 0; mi < 4; ++mi)
      #pragma unroll
      for (int s = 0; s < 2; ++s)
        kf[mi][s] = *(const short8*)(Kb + (size_t)(kt * 64 + mi * 16 + l15) * 64 + quad * 8 + 32 * s);
    // V^T as B-operand frags direct from global: lane n=d(jd*16+l15), k=tok
    short8 vf[4][2];
    #pragma unroll
    for (int jd = 0; jd < 4; ++jd)
      #pragma unroll
      for (int s = 0; s < 2; ++s)
        vf[jd][s] = *(const short8*)(Vb + (size_t)(jd * 16 + l15) * T + kt * 64 + s * 32 + quad * 8);

    // S^T = K·Q^T : rows=tok(64), cols=q(32)
    f32x4 S[4][2] = {};
    #pragma unroll
    for (int s = 0; s < 2; ++s)
      #pragma unroll
      for (int mi = 0; mi < 4; ++mi)
        #pragma unroll
        for (int jq = 0; jq < 2; ++jq)
          S[mi][jq] = __builtin_amdgcn_mfma_f32_16x16x32_bf16(kf[mi][s], qf[jq][s], S[mi][jq], 0, 0, 0);

    if (kt == qt) {  // diagonal tile: mask tok > q
      #pragma unroll
      for (int mi = 0; mi < 4; ++mi) {
        int tok = qt * 64 + mi * 16 + quad * 4;
        #pragma unroll
        for (int jq = 0; jq < 2; ++jq) {
          int q = qw + jq * 16 + l15;
          #pragma unroll
          for (int r = 0; r < 4; ++r)
            if (tok + r > q) S[mi][jq][r] = -__builtin_inff();
        }
      }
    }

    // online softmax along tok per jq-column-block
    float alpha[2];
    #pragma unroll
    for (int jq = 0; jq < 2; ++jq) {
      float vmax = -__builtin_inff();
      #pragma unroll
      for (int mi = 0; mi < 4; ++mi)
        #pragma unroll
        for (int r = 0; r < 4; ++r)
          vmax = fmaxf(vmax, S[mi][jq][r]);
      vmax = fmaxf(vmax, __shfl_xor(vmax, 16));
      vmax = fmaxf(vmax, __shfl_xor(vmax, 32));
      float mnew = fmaxf(m_run[jq], vmax);
      alpha[jq] = __expf(m_run[jq] - mnew);
      m_run[jq] = mnew;
      float rs = 0.f;
      #pragma unroll
      for (int mi = 0; mi < 4; ++mi) {
        float p0 = __expf(S[mi][jq][0] - mnew);
        float p1 = __expf(S[mi][jq][1] - mnew);
        float p2 = __expf(S[mi][jq][2] - mnew);
        float p3 = __expf(S[mi][jq][3] - mnew);
        rs += (p0 + p1) + (p2 + p3);
        union { float f; unsigned int u; } a0{p0}, a1{p1}, a2{p2}, a3{p3};
        uint2 pk;
        pk.x = ((a0.u + 0x8000u) >> 16) | ((a1.u + 0x8000u) & 0xFFFF0000u);
        pk.y = ((a2.u + 0x8000u) >> 16) | ((a3.u + 0x8000u) & 0xFFFF0000u);
        *(uint2*)&Ps[wave][(jq * 16 + l15) * 72 + mi * 16 + quad * 4] = pk;
      }
      rs += __shfl_xor(rs, 16);
      rs += __shfl_xor(rs, 32);
      l_run[jq] = l_run[jq] * alpha[jq] + rs;
    }

    // rescale O (alpha indexed by q at lane l15 -> redistribute to C rows)
    #pragma unroll
    for (int mq = 0; mq < 2; ++mq)
      #pragma unroll
      for (int r = 0; r < 4; ++r) {
        float a = __shfl(alpha[mq], quad * 4 + r);
        #pragma unroll
        for (int jd = 0; jd < 4; ++jd)
          Oacc[mq][jd][r] *= a;
      }

    // O += P·V  (A=P from LDS in A-layout, B=V^T frags)
    #pragma unroll
    for (int s = 0; s < 2; ++s) {
      short8 pf[2];
      #pragma unroll
      for (int mq = 0; mq < 2; ++mq)
        pf[mq] = *(const short8*)&Ps[wave][(mq * 16 + l15) * 72 + s * 32 + quad * 8];
      #pragma unroll
      for (int jd = 0; jd < 4; ++jd)
        #pragma unroll
        for (int mq = 0; mq < 2; ++mq)
          Oacc[mq][jd] = __builtin_amdgcn_mfma_f32_16x16x32_bf16(pf[mq], vf[jd][s], Oacc[mq][jd], 0, 0, 0);
    }
  }

  // finalize: O/l, write Y [b*T+q][h*64+d] bf16
  int h = bh & 15, b = bh >> 4;
  #pragma unroll
  for (int mq = 0; mq < 2; ++mq)
    #pragma unroll
    for (int r = 0; r < 4; ++r) {
      float linv = 1.f / __shfl(l_run[mq], quad * 4 + r);
      int q = qw + mq * 16 + quad * 4 + r;
      size_t row = (size_t)(b * 2048 + q) * 1024 + h * 64;
      #pragma unroll
      for (int jd = 0; jd < 4; ++jd)
        Yg[row + jd * 16 + l15] = f2bf(Oacc[mq][jd][r] * linv);
    }
}

// ---------------- out projection ----------------

__global__ void bias_init(const float* __restrict__ bo, float* __restrict__ out) {
  int t = blockIdx.x * 256 + threadIdx.x;  // 65536 float4s
  float4 b = *(const float4*)(bo + (t & 15) * 4);
  *(float4*)(out + (size_t)t * 4) = b;
}

__global__ __launch_bounds__(256) void oproj(
    const unsigned short* __restrict__ Y, const unsigned short* __restrict__ Wot,
    float* __restrict__ out) {
  __shared__ __align__(16) unsigned short As[64 * 32];
  __shared__ __align__(16) unsigned short Bs[64 * 32];
  int m0 = blockIdx.x * 64;
  int kbase = blockIdx.y * 256;  // 4-way split-K
  int tid = threadIdx.x, lane = tid & 63, wave = tid >> 6;
  int l15 = lane & 15, quad = lane >> 4;
  f32x4 acc[4] = {};
  for (int k0 = kbase; k0 < kbase + 256; k0 += 32) {
    __syncthreads();
    {
      int row = tid >> 2, c8 = (tid & 3) * 8;
      gload_lds16(Y + (size_t)(m0 + row) * 1024 + k0 + c8, &As[tid * 8]);
      gload_lds16(Wot + (size_t)row * 1024 + k0 + c8, &Bs[tid * 8]);
    }
    __syncthreads();
    short8 af = *(const short8*)&As[(wave * 16 + l15) * 32 + quad * 8];
    #pragma unroll
    for (int j = 0; j < 4; ++j) {
      short8 bf = *(const short8*)&Bs[(j * 16 + l15) * 32 + quad * 8];
      acc[j] = __builtin_amdgcn_mfma_f32_16x16x32_bf16(af, bf, acc[j], 0, 0, 0);
    }
  }
  #pragma unroll
  for (int j = 0; j < 4; ++j) {
    int n = j * 16 + l15;
    #pragma unroll
    for (int r = 0; r < 4; ++r) {
      int m = m0 + wave * 16 + quad * 4 + r;
      atomicAdd(&out[(size_t)m * 64 + n], acc[j][r]);
    }
  }
}

// ---------------- launcher ----------------

extern "C" void kernel_launch(void* const* d_in, const int* in_sizes, int n_in,
                              void* d_out, int out_size, void* d_ws, size_t ws_size,
                              hipStream_t stream) {
  const float* x  = (const float*)d_in[0];
  const float* Wq = (const float*)d_in[1];
  const float* Wk = (const float*)d_in[2];
  const float* Wv = (const float*)d_in[3];
  const float* Wo = (const float*)d_in[4];
  const float* bo = (const float*)d_in[5];
  float* out = (float*)d_out;
  char* ws = (char*)d_ws;

  unsigned short* xb  = (unsigned short*)(ws);                       // 8 MB  [4096][1024]
  unsigned short* wqt = (unsigned short*)(ws + (8ull << 20));        // 2 MB  Wq^T
  unsigned short* wkt = (unsigned short*)(ws + (10ull << 20));       // 2 MB
  unsigned short* wvt = (unsigned short*)(ws + (12ull << 20));       // 2 MB
  unsigned short* wot = (unsigned short*)(ws + (14ull << 20));       // 128 KB Wo^T
  unsigned short* q   = (unsigned short*)(ws + (15ull << 20));       // 8 MB  [b][h][t][d]
  unsigned short* k   = (unsigned short*)(ws + (23ull << 20));       // 8 MB  [b][h][t][d]
  unsigned short* vt  = (unsigned short*)(ws + (31ull << 20));       // 8 MB  [b][h][d][t]
  unsigned short* y   = (unsigned short*)(ws + (39ull << 20));       // 8 MB  [4096][1024]

  bias_init<<<256, 256, 0, stream>>>(bo, out);
  cvt_bf16<<<4096, 256, 0, stream>>>(x, xb, 4096 * 1024);
  transpose_cvt3<<<dim3(32, 32, 3), 256, 0, stream>>>(Wq, Wk, Wv, wqt, wkt, wvt);
  transpose_cvt<<<dim3(32, 2), 256, 0, stream>>>(Wo, wot, 1024, 64);
  qkv_gemm<<<dim3(32, 8, 3), 256, 0, stream>>>(xb, wqt, wkt, wvt, q, k, vt);
  attn3<<<dim3(32, 32), 128, 0, stream>>>(q, k, vt, y);
  oproj<<<dim3(64, 4), 256, 0, stream>>>(y, wot, out);
}

// Round 5
// 176.961 us; speedup vs baseline: 1.3054x; 1.3054x over previous
//
#include <hip/hip_runtime.h>

typedef __attribute__((ext_vector_type(8))) short short8;     // 8 bf16 MFMA operand
typedef __attribute__((ext_vector_type(4))) float f32x4;
typedef __attribute__((ext_vector_type(8))) unsigned short ushort8v;

// B=2, T=2048, D_IN=1024, H=16, D_HEAD=64, D_INNER=1024, M=B*T=4096

__device__ __forceinline__ unsigned short f2bf(float f) {
  union { float f; unsigned int u; } x; x.f = f;
  unsigned int r = x.u + 0x7FFFu + ((x.u >> 16) & 1u);   // RNE
  return (unsigned short)(r >> 16);
}

__device__ __forceinline__ void gload_lds16(const void* g, void* l) {
  __builtin_amdgcn_global_load_lds(
      (const __attribute__((address_space(1))) void*)g,
      (__attribute__((address_space(3))) void*)l, 16, 0, 0);
}

// ---------------- fused prep: bias_init + x->bf16 + 4 weight transposes ----------------
// One launch (saves per-kernel overhead). Branch is block-uniform.
// grid: [0,4096) cvt x | [4096,7168) Wq/Wk/Wv transpose | [7168,7232) Wo | [7232,7488) bias

__global__ __launch_bounds__(256) void prep(
    const float* __restrict__ x,
    const float* __restrict__ Wq, const float* __restrict__ Wk, const float* __restrict__ Wv,
    const float* __restrict__ Wo, const float* __restrict__ bo,
    unsigned short* __restrict__ xb,
    unsigned short* __restrict__ wqt, unsigned short* __restrict__ wkt,
    unsigned short* __restrict__ wvt, unsigned short* __restrict__ wot,
    float* __restrict__ out) {
  __shared__ float tile[32][33];
  int b = blockIdx.x;
  if (b < 4096) {                     // x -> bf16, 4 elems/thread
    int i = (b * 256 + threadIdx.x) * 4;
    float4 f = *(const float4*)(x + i);
    ushort4 o;
    o.x = f2bf(f.x); o.y = f2bf(f.y); o.z = f2bf(f.z); o.w = f2bf(f.w);
    *(ushort4*)(xb + i) = o;
  } else if (b < 7168) {              // W^T for Wq/Wk/Wv (1024x1024)
    int idx = b - 4096;
    int z = idx >> 10, rem = idx & 1023;
    const float* src = (z == 0) ? Wq : (z == 1) ? Wk : Wv;
    unsigned short* dst = (z == 0) ? wqt : (z == 1) ? wkt : wvt;
    int kx = (rem & 31) * 32, ny = (rem >> 5) * 32;
    int tx = threadIdx.x & 31, ty = threadIdx.x >> 5;
    #pragma unroll
    for (int r = 0; r < 32; r += 8)
      tile[ty + r][tx] = src[(size_t)(kx + ty + r) * 1024 + ny + tx];
    __syncthreads();
    #pragma unroll
    for (int r = 0; r < 32; r += 8)
      dst[(size_t)(ny + ty + r) * 1024 + kx + tx] = f2bf(tile[tx][ty + r]);
  } else if (b < 7232) {              // Wo^T (1024x64 -> 64x1024)
    int idx = b - 7168;
    int kx = (idx & 31) * 32, ny = (idx >> 5) * 32;
    int tx = threadIdx.x & 31, ty = threadIdx.x >> 5;
    #pragma unroll
    for (int r = 0; r < 32; r += 8)
      tile[ty + r][tx] = Wo[(size_t)(kx + ty + r) * 64 + ny + tx];
    __syncthreads();
    #pragma unroll
    for (int r = 0; r < 32; r += 8)
      wot[(size_t)(ny + ty + r) * 1024 + kx + tx] = f2bf(tile[tx][ty + r]);
  } else {                            // seed out with bias (out is re-poisoned each call)
    int t = (b - 7232) * 256 + threadIdx.x;  // 65536 float4s
    float4 bi = *(const float4*)(bo + (t & 15) * 4);
    *(float4*)(out + (size_t)t * 4) = bi;
  }
}

// ---------------- QKV projection GEMM, BK=64 with XOR-swizzled staging ----------------
// z=0: Q = x·Wq (scaled 1/32) -> [b][h][t][d]; z=1: K -> [b][h][t][d];
// z=2: V^T computed directly (A=Wv^T, B=x) -> [b][h][d][t]

__global__ __launch_bounds__(256) void qkv_gemm(
    const unsigned short* __restrict__ Xb,
    const unsigned short* __restrict__ Wqt, const unsigned short* __restrict__ Wkt,
    const unsigned short* __restrict__ Wvt,
    unsigned short* __restrict__ Oq, unsigned short* __restrict__ Ok,
    unsigned short* __restrict__ Ovt) {
  constexpr int Kd = 1024;
  __shared__ __align__(16) unsigned short As[128 * 64];
  __shared__ __align__(16) unsigned short Bs[128 * 64];
  int z = blockIdx.z;
  int m0, n0;
  const unsigned short *Arow, *Brow;
  if (z == 2) {
    m0 = blockIdx.y * 128; n0 = blockIdx.x * 128;
    Arow = Wvt; Brow = Xb;
  } else {
    m0 = blockIdx.x * 128; n0 = blockIdx.y * 128;
    Arow = Xb; Brow = (z == 0) ? Wqt : Wkt;
  }
  int tid = threadIdx.x, lane = tid & 63, wave = tid >> 6;
  int wm = wave >> 1, wn = wave & 1;
  int l15 = lane & 15, quad = lane >> 4;
  int swz = l15 & 7;

  f32x4 acc[4][4] = {};

  for (int k0 = 0; k0 < Kd; k0 += 64) {
    __syncthreads();
    #pragma unroll
    for (int r = 0; r < 4; ++r) {
      int i = tid + 256 * r;
      int row = i >> 3, c8 = i & 7;
      int gc8 = c8 ^ (row & 7);
      gload_lds16(Arow + (size_t)(m0 + row) * Kd + k0 + gc8 * 8, &As[i * 8]);
    }
    #pragma unroll
    for (int r = 0; r < 4; ++r) {
      int i = tid + 256 * r;
      int row = i >> 3, c8 = i & 7;
      int gc8 = c8 ^ (row & 7);
      gload_lds16(Brow + (size_t)(n0 + row) * Kd + k0 + gc8 * 8, &Bs[i * 8]);
    }
    __syncthreads();
    short8 af[4][2], bf[4][2];
    #pragma unroll
    for (int s = 0; s < 2; ++s) {
      #pragma unroll
      for (int i = 0; i < 4; ++i)
        af[i][s] = *(const short8*)&As[(wm * 64 + i * 16 + l15) * 64 + (((s << 2) + quad) ^ swz) * 8];
      #pragma unroll
      for (int j = 0; j < 4; ++j)
        bf[j][s] = *(const short8*)&Bs[(wn * 64 + j * 16 + l15) * 64 + (((s << 2) + quad) ^ swz) * 8];
    }
    #pragma unroll
    for (int s = 0; s < 2; ++s)
      #pragma unroll
      for (int i = 0; i < 4; ++i)
        #pragma unroll
        for (int j = 0; j < 4; ++j)
          acc[i][j] = __builtin_amdgcn_mfma_f32_16x16x32_bf16(af[i][s], bf[j][s], acc[i][j], 0, 0, 0);
  }

  if (z == 2) {
    #pragma unroll
    for (int i = 0; i < 4; ++i) {
      int dmbase = m0 + wm * 64 + i * 16 + quad * 4;
      #pragma unroll
      for (int j = 0; j < 4; ++j) {
        int tn = n0 + wn * 64 + j * 16 + l15;
        int b = tn >> 11, t = tn & 2047;
        #pragma unroll
        for (int r = 0; r < 4; ++r) {
          int dm = dmbase + r;
          int h = dm >> 6, d = dm & 63;
          Ovt[(((size_t)(b * 16 + h) * 64 + d) << 11) + t] = f2bf(acc[i][j][r]);
        }
      }
    }
  } else {
    unsigned short* O = (z == 0) ? Oq : Ok;
    float scale = (z == 0) ? 0.03125f : 1.0f;  // 1/sqrt(1024) folded into Q
    #pragma unroll
    for (int i = 0; i < 4; ++i) {
      int mbase = m0 + wm * 64 + i * 16 + quad * 4;
      #pragma unroll
      for (int j = 0; j < 4; ++j) {
        int n = n0 + wn * 64 + j * 16 + l15;
        int h = n >> 6, d = n & 63;
        #pragma unroll
        for (int r = 0; r < 4; ++r) {
          int mm = mbase + r;
          int b = mm >> 11, t = mm & 2047;
          size_t off = (((size_t)(b * 16 + h) * 2048 + t) << 6) + d;
          O[off] = f2bf(acc[i][j][r] * scale);
        }
      }
    }
  }
}

// ---------------- fused causal flash attention v4: balanced pairing ----------------
// Each block handles TWO 64-row q-tiles: qt=p and qt=31-p -> 33 k-tile trips
// uniformly (no drain tail; all blocks equal work). Inner body = proven attn2:
// LDS-staged K/V (reg prefetch), pad-72 rows, P round-trip via LDS.
// grid (16, 32) = 512 blocks, 4 waves, 16 q/wave per phase.

__global__ __launch_bounds__(256, 4) void attn4(
    const unsigned short* __restrict__ Qg, const unsigned short* __restrict__ Kg,
    const unsigned short* __restrict__ Vtg, unsigned short* __restrict__ Yg) {
  constexpr int T = 2048;
  __shared__ __align__(16) unsigned short Ks[64 * 72];
  __shared__ __align__(16) unsigned short Vs[64 * 72];
  __shared__ __align__(16) unsigned short Ps[4][16 * 72];
  int bh = blockIdx.y;
  int p = (blockIdx.x + blockIdx.y) & 15;   // L2 swizzle over pairs
  int tid = threadIdx.x, lane = tid & 63, wave = tid >> 6;
  int l15 = lane & 15, quad = lane >> 4;
  const unsigned short* Qb = Qg + (size_t)bh * T * 64;
  const unsigned short* Kb = Kg + (size_t)bh * T * 64;
  const unsigned short* Vb = Vtg + (size_t)bh * 64 * T;
  int h = bh & 15, b = bh >> 4;

  for (int phase = 0; phase < 2; ++phase) {
    int qt = phase ? (31 - p) : p;
    int qw = qt * 64 + wave * 16;

    // Q as B-operand frags (held in regs): B[k=d][n=q] from Q[q][d]
    short8 qf[2];
    #pragma unroll
    for (int s = 0; s < 2; ++s)
      qf[s] = *(const short8*)(Qb + (size_t)(qw + l15) * 64 + quad * 8 + 32 * s);

    f32x4 Oacc[4] = {};
    float m_run = -__builtin_inff(), l_run = 0.f;

    // prefetch tile 0
    ushort8v kpre[2], vpre[2];
    #pragma unroll
    for (int r = 0; r < 2; ++r) {
      int i = tid + 256 * r;
      kpre[r] = *(const ushort8v*)(Kb + (size_t)(i >> 3) * 64 + (i & 7) * 8);
      vpre[r] = *(const ushort8v*)(Vb + (size_t)(i >> 3) * T + (i & 7) * 8);
    }

    for (int kt = 0; kt <= qt; ++kt) {
      __syncthreads();
      #pragma unroll
      for (int r = 0; r < 2; ++r) {
        int i = tid + 256 * r;
        *(ushort8v*)&Ks[(i >> 3) * 72 + (i & 7) * 8] = kpre[r];
        *(ushort8v*)&Vs[(i >> 3) * 72 + (i & 7) * 8] = vpre[r];
      }
      __syncthreads();
      if (kt < qt) {  // prefetch next tile while computing
        #pragma unroll
        for (int r = 0; r < 2; ++r) {
          int i = tid + 256 * r;
          kpre[r] = *(const ushort8v*)(Kb + (size_t)((kt + 1) * 64 + (i >> 3)) * 64 + (i & 7) * 8);
          vpre[r] = *(const ushort8v*)(Vb + (size_t)(i >> 3) * T + (kt + 1) * 64 + (i & 7) * 8);
        }
      }

      // S^T = K·Q^T : rows=tok(64), cols=q(16)
      f32x4 S[4] = {};
      #pragma unroll
      for (int s = 0; s < 2; ++s)
        #pragma unroll
        for (int mi = 0; mi < 4; ++mi) {
          short8 kf = *(const short8*)&Ks[(mi * 16 + l15) * 72 + quad * 8 + 32 * s];
          S[mi] = __builtin_amdgcn_mfma_f32_16x16x32_bf16(kf, qf[s], S[mi], 0, 0, 0);
        }

      if (kt == qt) {  // diagonal tile: mask tok_local > q_local
        int ql = wave * 16 + l15;
        #pragma unroll
        for (int mi = 0; mi < 4; ++mi) {
          int tokl = mi * 16 + quad * 4;
          #pragma unroll
          for (int r = 0; r < 4; ++r)
            if (tokl + r > ql) S[mi][r] = -__builtin_inff();
        }
      }

      // online softmax along tok
      float vmax = -__builtin_inff();
      #pragma unroll
      for (int mi = 0; mi < 4; ++mi)
        #pragma unroll
        for (int r = 0; r < 4; ++r)
          vmax = fmaxf(vmax, S[mi][r]);
      vmax = fmaxf(vmax, __shfl_xor(vmax, 16));
      vmax = fmaxf(vmax, __shfl_xor(vmax, 32));
      float mnew = fmaxf(m_run, vmax);
      float alpha = __expf(m_run - mnew);
      m_run = mnew;
      float rs = 0.f;
      #pragma unroll
      for (int mi = 0; mi < 4; ++mi) {
        float p0 = __expf(S[mi][0] - mnew);
        float p1 = __expf(S[mi][1] - mnew);
        float p2 = __expf(S[mi][2] - mnew);
        float p3 = __expf(S[mi][3] - mnew);
        rs += (p0 + p1) + (p2 + p3);
        union { float f; unsigned int u; } a0{p0}, a1{p1}, a2{p2}, a3{p3};
        uint2 pk;
        pk.x = ((a0.u + 0x8000u) >> 16) | ((a1.u + 0x8000u) & 0xFFFF0000u);
        pk.y = ((a2.u + 0x8000u) >> 16) | ((a3.u + 0x8000u) & 0xFFFF0000u);
        *(uint2*)&Ps[wave][l15 * 72 + mi * 16 + quad * 4] = pk;
      }
      rs += __shfl_xor(rs, 16);
      rs += __shfl_xor(rs, 32);
      l_run = l_run * alpha + rs;

      // rescale O (alpha indexed by q=l15 -> redistribute to C rows quad*4+r)
      #pragma unroll
      for (int r = 0; r < 4; ++r) {
        float a = __shfl(alpha, quad * 4 + r);
        #pragma unroll
        for (int jd = 0; jd < 4; ++jd)
          Oacc[jd][r] *= a;
      }

      // O += P·V  (A=P[q][tok], B=V^T[d][tok])
      #pragma unroll
      for (int s = 0; s < 2; ++s) {
        short8 pf = *(const short8*)&Ps[wave][l15 * 72 + quad * 8 + 32 * s];
        #pragma unroll
        for (int jd = 0; jd < 4; ++jd) {
          short8 vf = *(const short8*)&Vs[(jd * 16 + l15) * 72 + quad * 8 + 32 * s];
          Oacc[jd] = __builtin_amdgcn_mfma_f32_16x16x32_bf16(pf, vf, Oacc[jd], 0, 0, 0);
        }
      }
    }

    // finalize phase: O/l, write Y [b*T+q][h*64+d] bf16
    #pragma unroll
    for (int r = 0; r < 4; ++r) {
      float linv = 1.f / __shfl(l_run, quad * 4 + r);
      int q = qw + quad * 4 + r;
      size_t row = (size_t)(b * 2048 + q) * 1024 + h * 64;
      #pragma unroll
      for (int jd = 0; jd < 4; ++jd)
        Yg[row + jd * 16 + l15] = f2bf(Oacc[jd][r] * linv);
    }
  }
}

// ---------------- out projection: split-K atomics onto bias-seeded out ----------------

__global__ __launch_bounds__(256) void oproj(
    const unsigned short* __restrict__ Y, const unsigned short* __restrict__ Wot,
    float* __restrict__ out) {
  __shared__ __align__(16) unsigned short As[64 * 32];
  __shared__ __align__(16) unsigned short Bs[64 * 32];
  int m0 = blockIdx.x * 64;
  int kbase = blockIdx.y * 256;  // 4-way split-K
  int tid = threadIdx.x, lane = tid & 63, wave = tid >> 6;
  int l15 = lane & 15, quad = lane >> 4;
  f32x4 acc[4] = {};
  for (int k0 = kbase; k0 < kbase + 256; k0 += 32) {
    __syncthreads();
    {
      int row = tid >> 2, c8 = (tid & 3) * 8;
      gload_lds16(Y + (size_t)(m0 + row) * 1024 + k0 + c8, &As[tid * 8]);
      gload_lds16(Wot + (size_t)row * 1024 + k0 + c8, &Bs[tid * 8]);
    }
    __syncthreads();
    short8 af = *(const short8*)&As[(wave * 16 + l15) * 32 + quad * 8];
    #pragma unroll
    for (int j = 0; j < 4; ++j) {
      short8 bf = *(const short8*)&Bs[(j * 16 + l15) * 32 + quad * 8];
      acc[j] = __builtin_amdgcn_mfma_f32_16x16x32_bf16(af, bf, acc[j], 0, 0, 0);
    }
  }
  #pragma unroll
  for (int j = 0; j < 4; ++j) {
    int n = j * 16 + l15;
    #pragma unroll
    for (int r = 0; r < 4; ++r) {
      int m = m0 + wave * 16 + quad * 4 + r;
      atomicAdd(&out[(size_t)m * 64 + n], acc[j][r]);
    }
  }
}

// ---------------- launcher (4 kernels total) ----------------

extern "C" void kernel_launch(void* const* d_in, const int* in_sizes, int n_in,
                              void* d_out, int out_size, void* d_ws, size_t ws_size,
                              hipStream_t stream) {
  const float* x  = (const float*)d_in[0];
  const float* Wq = (const float*)d_in[1];
  const float* Wk = (const float*)d_in[2];
  const float* Wv = (const float*)d_in[3];
  const float* Wo = (const float*)d_in[4];
  const float* bo = (const float*)d_in[5];
  float* out = (float*)d_out;
  char* ws = (char*)d_ws;

  unsigned short* xb  = (unsigned short*)(ws);                       // 8 MB  [4096][1024]
  unsigned short* wqt = (unsigned short*)(ws + (8ull << 20));        // 2 MB  Wq^T
  unsigned short* wkt = (unsigned short*)(ws + (10ull << 20));       // 2 MB
  unsigned short* wvt = (unsigned short*)(ws + (12ull << 20));       // 2 MB
  unsigned short* wot = (unsigned short*)(ws + (14ull << 20));       // 128 KB Wo^T
  unsigned short* q   = (unsigned short*)(ws + (15ull << 20));       // 8 MB  [b][h][t][d]
  unsigned short* k   = (unsigned short*)(ws + (23ull << 20));       // 8 MB  [b][h][t][d]
  unsigned short* vt  = (unsigned short*)(ws + (31ull << 20));       // 8 MB  [b][h][d][t]
  unsigned short* y   = (unsigned short*)(ws + (39ull << 20));       // 8 MB  [4096][1024]

  prep<<<7488, 256, 0, stream>>>(x, Wq, Wk, Wv, Wo, bo, xb, wqt, wkt, wvt, wot, out);
  qkv_gemm<<<dim3(32, 8, 3), 256, 0, stream>>>(xb, wqt, wkt, wvt, q, k, vt);
  attn4<<<dim3(16, 32), 256, 0, stream>>>(q, k, vt, y);
  oproj<<<dim3(64, 4), 256, 0, stream>>>(y, wot, out);
}